// Round 7
// baseline (2546.812 us; speedup 1.0000x reference)
//
#include <hip/hip_runtime.h>
#include <hip/hip_bf16.h>

#define BB 256
#define SS 32
#define II 128
#define HH 256
#define LBL 200
#define NSUBS 491
#define NATOMS_N 8000
#define NMOL_N 600

typedef const float* fp;

__device__ __forceinline__ float sigm(float x) { return 1.f / (1.f + expf(-x)); }

// ---------------------------------------------------------------------------
// prep (14 blocks): idxv, mstart, masked w_masklin, zero h ping-pong + barrier
// ---------------------------------------------------------------------------
__global__ __launch_bounds__(256) void prep_kernel(
    const int* __restrict__ mask, int* __restrict__ idxv,
    const int* __restrict__ seg, int* __restrict__ mstart,
    fp w_masklin, fp ddi, float* __restrict__ mw,
    float* __restrict__ hzero, int* __restrict__ bar)
{
  int bx = blockIdx.x, tid = threadIdx.x;
  if (bx == 0) {                         // idx[b] = clamp(sum(mask[b,:]) - 1)
    int s = 0;
    const int* mrow = mask + tid * SS;
    for (int t = 0; t < SS; ++t) s += mrow[t];
    s -= 1;
    if (s < 0) s = 0;
    if (s > SS - 1) s = SS - 1;
    idxv[tid] = s;
  } else if (bx == 1) {                  // mstart[m] = lower_bound(seg, m)
    for (int m = tid; m <= NMOL_N; m += 256) {
      if (m == NMOL_N) { mstart[m] = NATOMS_N; continue; }
      int lo = 0, hi = NATOMS_N;
      while (lo < hi) {
        int mid = (lo + hi) >> 1;
        if (seg[mid] < m) lo = mid + 1; else hi = mid;
      }
      mstart[m] = lo;
    }
    if (tid == 0) { bar[0] = 0; bar[1] = 0; }
  } else if (bx < 6) {                   // mw[s][l] = w_masklin[s][l]*ddi[l][s]
    for (int o = (bx - 2) * 256 + tid; o < NSUBS * LBL; o += 4 * 256) {
      int s = o / LBL, l = o - s * LBL;
      mw[o] = w_masklin[o] * ddi[l * NSUBS + s];
    }
  } else {                               // zero hX+hY (262144 floats, 8 blocks)
    float* p = hzero + (size_t)(bx - 6) * 32768;
    for (int o = tid; o < 32768; o += 256) p[o] = 0.f;
  }
}

// ---------------------------------------------------------------------------
// xp = x @ w_ih.T + b_ih, fp32. xp[g][b*SS+t][768], 8192 rows per g.
// grid (24576, 2): 512 mtiles x 48 ntiles
// ---------------------------------------------------------------------------
__global__ __launch_bounds__(256) void xp_gemm(
    fp x_c, fp x_p, fp wih_c, fp wih_p, fp bih_c, fp bih_p,
    float* __restrict__ xp)
{
  int g = blockIdx.y;
  fp x = g ? x_p : x_c;
  fp wih = g ? wih_p : wih_c;
  fp bih = g ? bih_p : bih_c;
  float* xpo = xp + (size_t)g * 8192 * 768;

  int bx = blockIdx.x;
  int mt = bx / 48, nt = bx - mt * 48;
  int m0 = mt << 4, n0 = nt << 4;
  int tid = threadIdx.x;

  __shared__ float As[16][132];
  __shared__ float Ws[16][132];
  for (int i = tid; i < 2048; i += 256) {
    int r = i >> 7, k = i & 127;
    As[r][k] = x[(size_t)(m0 + r) * II + k];
    Ws[r][k] = wih[(size_t)(n0 + r) * II + k];
  }
  __syncthreads();

  int ni = tid & 15, mi = tid >> 4;
  float acc = 0.f;
#pragma unroll 8
  for (int k = 0; k < II; ++k) acc = fmaf(As[mi][k], Ws[ni][k], acc);
  xpo[(size_t)(m0 + mi) * 768 + n0 + ni] = acc + bih[n0 + ni];
}

// ---------------------------------------------------------------------------
// fully-fused MPNN: one block per molecule (<=14 atoms).
// ---------------------------------------------------------------------------
__global__ __launch_bounds__(256) void mpnn_mol(
    const int* __restrict__ fingerprints, fp embed_fp, fp adj,
    const int* __restrict__ mstart, fp w_g0, fp b_g0, fp w_g1, fp b_g1,
    float* __restrict__ mol)
{
  int m = blockIdx.x, tid = threadIdx.x;
  int a0 = mstart[m], a1 = mstart[m + 1];
  int sz = a1 - a0;
  if (sz < 0) sz = 0;
  if (sz > 14) sz = 14;

  __shared__ float v[14][260];
  __shared__ float adjb[14][16];

#pragma unroll
  for (int i = 0; i < 14; ++i) {
    float val = 0.f;
    if (i < sz) {
      int f = fingerprints[a0 + i] & 1023;
      val = embed_fp[(size_t)f * HH + tid];
    }
    v[i][tid] = val;
  }
  if (tid < 224) {
    int i = tid >> 4, jj = tid & 15;
    float a = 0.f;
    if (i < sz && jj < sz)
      a = adj[(size_t)(a0 + i) * NATOMS_N + a0 + jj];
    adjb[i][jj] = a;
  }
  __syncthreads();

  float acc[14];
  for (int rd = 0; rd < 2; ++rd) {
    const float* wp0 = (rd ? w_g1 : w_g0) + tid;
#pragma unroll
    for (int i = 0; i < 14; ++i) acc[i] = 0.f;
    for (int k = 0; k < HH; k += 4) {
      float w0 = wp0[(size_t)k * HH];
      float w1 = wp0[(size_t)(k + 1) * HH];
      float w2 = wp0[(size_t)(k + 2) * HH];
      float w3 = wp0[(size_t)(k + 3) * HH];
#pragma unroll
      for (int i = 0; i < 14; ++i) {
        float4 vv = *(const float4*)&v[i][k];
        acc[i] = fmaf(vv.x, w0, acc[i]);
        acc[i] = fmaf(vv.y, w1, acc[i]);
        acc[i] = fmaf(vv.z, w2, acc[i]);
        acc[i] = fmaf(vv.w, w3, acc[i]);
      }
    }
    float bias = (rd ? b_g1 : b_g0)[tid];
    float hreg[14];
#pragma unroll
    for (int i = 0; i < 14; ++i) hreg[i] = fmaxf(acc[i] + bias, 0.f);
#pragma unroll
    for (int i = 0; i < 14; ++i) {
      float s = hreg[i];
#pragma unroll
      for (int jj = 0; jj < 14; ++jj) s = fmaf(adjb[i][jj], hreg[jj], s);
      acc[i] = s;
    }
    if (rd == 0) {
      __syncthreads();
#pragma unroll
      for (int i = 0; i < 14; ++i) v[i][tid] = acc[i];
      __syncthreads();
    }
  }
  float msum = 0.f;
#pragma unroll
  for (int i = 0; i < 14; ++i) if (i < sz) msum += acc[i];
  mol[(size_t)m * HH + tid] = msum;
}

// ---------------------------------------------------------------------------
// mpnn_emb^T[h][d] = sum_m avg[d][m] * mol[m][h]
// ---------------------------------------------------------------------------
__global__ __launch_bounds__(256) void mpnn_emb_k(
    fp avg, const float* __restrict__ mol, float* __restrict__ embT)
{
  int d = blockIdx.x, tid = threadIdx.x;
  float acc = 0.f;
  for (int m = 0; m < NMOL_N; ++m)
    acc += avg[d * NMOL_N + m] * mol[(size_t)m * HH + tid];
  embT[(size_t)tid * LBL + d] = acc;
}

// ---------------------------------------------------------------------------
// persistent GRU: 256 blocks (1/CU, co-resident), all 32 steps in one launch.
// block = (g, btile of 32 batches, jtile of 16 j). w_hh slice staged in LDS
// once; per step: stage h tile, 6 dot products/thread, epilogue, grid barrier.
// ---------------------------------------------------------------------------
__global__ __launch_bounds__(256) void gru_persist(
    fp xp, fp whh_c, fp whh_p, fp bhh_c, fp bhh_p,
    float* __restrict__ hX, float* __restrict__ hY,
    float* __restrict__ hcat, const int* __restrict__ idxv,
    int* bar)
{
  int blk = blockIdx.x;
  int g = blk >> 7;
  int rem = blk & 127;
  int bt = rem >> 4;             // 0..7  -> 32 batches
  int jt = rem & 15;             // 0..15 -> 16 j
  int b0 = bt << 5, j0 = jt << 4;
  int tid = threadIdx.x;
  int ji = tid & 15, bi = tid >> 4;
  int j = j0 + ji;

  fp whh = g ? whh_p : whh_c;
  fp bhh = g ? bhh_p : bhh_c;

  __shared__ float wl[3][16][260];     // [gate][jj][k], pad 260
  __shared__ float hsd[32][260];       // [batch-local][k], pad 260

  // stage weight slice once: 48 rows (gate*256 + j0 + jj) x 256 k
  for (int i = tid; i < 48 * 64; i += 256) {
    int row = i >> 6, seg = i & 63;
    int gate = row >> 4, jj = row & 15;
    float4 vv = *(const float4*)(whh + ((size_t)(gate * 256 + j0 + jj)) * HH + seg * 4);
    *(float4*)&wl[gate][jj][seg * 4] = vv;
  }
  float br = bhh[j], bz = bhh[j + 256], bn = bhh[j + 512];
  int b1 = b0 + bi, b2 = b0 + bi + 16;
  int id1 = idxv[b1], id2 = idxv[b2];
  const float* xpg = xp + (size_t)g * 8192 * 768;
  __syncthreads();

  for (int t = 0; t < SS; ++t) {
    const float* src = ((t & 1) ? hY : hX) + (size_t)g * 65536 + (size_t)b0 * HH;
    float* dst = ((t & 1) ? hX : hY) + (size_t)g * 65536 + (size_t)b0 * HH;
    for (int i = tid; i < 32 * HH; i += 256)
      hsd[i >> 8][i & 255] = src[i];
    __syncthreads();

    float s1r = 0.f, s1z = 0.f, s1n = 0.f, s2r = 0.f, s2z = 0.f, s2n = 0.f;
    const float* h1p = hsd[bi];
    const float* h2p = hsd[bi + 16];
#pragma unroll 2
    for (int k = 0; k < HH; k += 4) {
      float4 wr = *(const float4*)&wl[0][ji][k];
      float4 wz = *(const float4*)&wl[1][ji][k];
      float4 wn = *(const float4*)&wl[2][ji][k];
      float4 h1 = *(const float4*)(h1p + k);
      float4 h2 = *(const float4*)(h2p + k);
      s1r = fmaf(h1.x, wr.x, s1r); s1r = fmaf(h1.y, wr.y, s1r);
      s1r = fmaf(h1.z, wr.z, s1r); s1r = fmaf(h1.w, wr.w, s1r);
      s1z = fmaf(h1.x, wz.x, s1z); s1z = fmaf(h1.y, wz.y, s1z);
      s1z = fmaf(h1.z, wz.z, s1z); s1z = fmaf(h1.w, wz.w, s1z);
      s1n = fmaf(h1.x, wn.x, s1n); s1n = fmaf(h1.y, wn.y, s1n);
      s1n = fmaf(h1.z, wn.z, s1n); s1n = fmaf(h1.w, wn.w, s1n);
      s2r = fmaf(h2.x, wr.x, s2r); s2r = fmaf(h2.y, wr.y, s2r);
      s2r = fmaf(h2.z, wr.z, s2r); s2r = fmaf(h2.w, wr.w, s2r);
      s2z = fmaf(h2.x, wz.x, s2z); s2z = fmaf(h2.y, wz.y, s2z);
      s2z = fmaf(h2.z, wz.z, s2z); s2z = fmaf(h2.w, wz.w, s2z);
      s2n = fmaf(h2.x, wn.x, s2n); s2n = fmaf(h2.y, wn.y, s2n);
      s2n = fmaf(h2.z, wn.z, s2n); s2n = fmaf(h2.w, wn.w, s2n);
    }
    {
      const float* xrow = xpg + ((size_t)b1 * SS + t) * 768;
      float r = sigm(xrow[j] + s1r + br);
      float z = sigm(xrow[j + 256] + s1z + bz);
      float n = tanhf(xrow[j + 512] + r * (s1n + bn));
      float hnew = (1.f - z) * n + z * h1p[j];
      dst[(size_t)bi * HH + j] = hnew;
      if (t == id1) hcat[(size_t)b1 * 512 + g * 256 + j] = fmaxf(hnew, 0.f);
    }
    {
      const float* xrow = xpg + ((size_t)b2 * SS + t) * 768;
      float r = sigm(xrow[j] + s2r + br);
      float z = sigm(xrow[j + 256] + s2z + bz);
      float n = tanhf(xrow[j + 512] + r * (s2n + bn));
      float hnew = (1.f - z) * n + z * h2p[j];
      dst[(size_t)(bi + 16) * HH + j] = hnew;
      if (t == id2) hcat[(size_t)b2 * 512 + g * 256 + j] = fmaxf(hnew, 0.f);
    }
    // release my writes, then grid barrier, then acquire
    __threadfence();
    __syncthreads();
    if (tid == 0) {
      int a = atomicAdd(bar, 1);
      if (a == 255) {
        atomicExch(bar, 0);
        __threadfence();
        atomicAdd(bar + 1, 1);
      } else {
        while (__hip_atomic_load(bar + 1, __ATOMIC_ACQUIRE,
                                 __HIP_MEMORY_SCOPE_AGENT) <= t) {
          __builtin_amdgcn_s_sleep(8);
        }
      }
    }
    __syncthreads();
    __threadfence();
  }
}

// ---------------------------------------------------------------------------
// fp32 GEMM for query: C[M,N] = A[M,K] @ W[K,N] + bias
// ---------------------------------------------------------------------------
__global__ __launch_bounds__(256) void gemm_f32(
    const float* __restrict__ A, fp W, fp bias, float* __restrict__ C,
    int M, int N, int K)
{
  int ntiles = N >> 4;
  int mt = blockIdx.x / ntiles, nt = blockIdx.x - mt * ntiles;
  int m0 = mt << 4, n0 = nt << 4;
  int tid = threadIdx.x;
  int ni = tid & 15, mi = tid >> 4;
  __shared__ float As[16][68];
  float acc = 0.f;
  for (int k0 = 0; k0 < K; k0 += 64) {
    __syncthreads();
    for (int i = tid; i < 1024; i += 256) {
      int r = i >> 6, kk = i & 63;
      As[r][kk] = A[(size_t)(m0 + r) * K + k0 + kk];
    }
    __syncthreads();
    const float* wp = W + (size_t)k0 * N + n0 + ni;
#pragma unroll 4
    for (int kk = 0; kk < 64; ++kk)
      acc = fmaf(As[mi][kk], wp[(size_t)kk * N], acc);
  }
  acc += bias[n0 + ni];
  C[(size_t)(m0 + mi) * N + n0 + ni] = acc;
}

// ---------------------------------------------------------------------------
// fused tail per batch row: match/x2/LN (mpnn_att) + bip/masked-linear + mul
// ---------------------------------------------------------------------------
__global__ __launch_bounds__(256) void tail_fused(
    const float* __restrict__ query, const float* __restrict__ embT,
    fp w_out, fp b_out, fp gamma, fp beta,
    fp w_bip, fp b_bip, const float* __restrict__ mw,
    float* __restrict__ out)
{
  int b = blockIdx.x, tid = threadIdx.x;
  __shared__ float q[HH];
  __shared__ float mrow[LBL];
  __shared__ float bips[NSUBS];
  __shared__ float red[256];
  q[tid] = query[(size_t)b * HH + tid];
  __syncthreads();
  if (tid < LBL) {
    float acc = 0.f;
    for (int k = 0; k < HH; ++k) acc += q[k] * embT[(size_t)k * LBL + tid];
    mrow[tid] = sigm(acc);
  }
  for (int s = tid; s < NSUBS; s += 256) {
    float acc = b_bip[s];
    for (int k = 0; k < HH; ++k) acc += q[k] * w_bip[(size_t)k * NSUBS + s];
    bips[s] = acc;
  }
  __syncthreads();
  float x2 = 0.f;
  if (tid < LBL) {
    float acc = b_out[tid] + mrow[tid];
    for (int jj = 0; jj < LBL; ++jj) acc += mrow[jj] * w_out[jj * LBL + tid];
    x2 = acc;
  }
  red[tid] = (tid < LBL) ? x2 : 0.f;
  __syncthreads();
  for (int s = 128; s > 0; s >>= 1) {
    if (tid < s) red[tid] += red[tid + s];
    __syncthreads();
  }
  float mu = red[0] / (float)LBL;
  __syncthreads();
  float dv = (tid < LBL) ? (x2 - mu) : 0.f;
  red[tid] = dv * dv;
  __syncthreads();
  for (int s = 128; s > 0; s >>= 1) {
    if (tid < s) red[tid] += red[tid + s];
    __syncthreads();
  }
  float var = red[0] / (float)LBL;
  if (tid < LBL) {
    float matt = (x2 - mu) * rsqrtf(var + 1e-5f) * gamma[tid] + beta[tid];
    float acc = 0.f;
    for (int s = 0; s < NSUBS; ++s) acc += bips[s] * mw[(size_t)s * LBL + tid];
    out[(size_t)b * LBL + tid] = acc * matt;
  }
}

// ---------------------------------------------------------------------------
extern "C" void kernel_launch(void* const* d_in, const int* in_sizes, int n_in,
                              void* d_out, int out_size, void* d_ws, size_t ws_size,
                              hipStream_t stream)
{
  fp x_c   = (fp)d_in[0];
  fp x_p   = (fp)d_in[1];
  const int* mask = (const int*)d_in[2];
  fp wih_c = (fp)d_in[3];
  fp whh_c = (fp)d_in[4];
  fp bih_c = (fp)d_in[5];
  fp bhh_c = (fp)d_in[6];
  fp wih_p = (fp)d_in[7];
  fp whh_p = (fp)d_in[8];
  fp bih_p = (fp)d_in[9];
  fp bhh_p = (fp)d_in[10];
  fp w_query = (fp)d_in[11];
  fp b_query = (fp)d_in[12];
  fp w_bip = (fp)d_in[13];
  fp b_bip = (fp)d_in[14];
  fp w_masklin = (fp)d_in[15];
  fp ddi = (fp)d_in[16];
  fp embed_fp = (fp)d_in[17];
  const int* fingerprints = (const int*)d_in[18];
  fp adj = (fp)d_in[19];
  const int* seg = (const int*)d_in[20];
  fp w_g0 = (fp)d_in[21];
  fp b_g0 = (fp)d_in[22];
  fp w_g1 = (fp)d_in[23];
  fp b_g1 = (fp)d_in[24];
  fp avg = (fp)d_in[25];
  fp w_out = (fp)d_in[26];
  fp b_out = (fp)d_in[27];
  fp gamma = (fp)d_in[28];
  fp beta = (fp)d_in[29];
  float* out = (float*)d_out;

  char* w = (char*)d_ws;
  size_t off = 0;
  auto alloc = [&](size_t bytes) -> void* {
    void* p = w + off;
    off = (off + bytes + 255) & ~(size_t)255;
    return p;
  };

  float* xp   = (float*)alloc((size_t)2 * 8192 * 768 * 4);   // 50.3 MB
  float* hX   = (float*)alloc((size_t)2 * 256 * HH * 4);     // 512 KB
  float* hY   = (float*)alloc((size_t)2 * 256 * HH * 4);     // 512 KB
  float* mol  = (float*)alloc((size_t)NMOL_N * HH * 4);
  float* embT = (float*)alloc((size_t)HH * LBL * 4);
  float* hcat = (float*)alloc((size_t)BB * 2 * HH * 4);
  float* query = (float*)alloc((size_t)BB * HH * 4);
  float* mw   = (float*)alloc((size_t)NSUBS * LBL * 4);
  int* idxv   = (int*)alloc(256 * 4);
  int* mstart = (int*)alloc((NMOL_N + 1) * 4);
  int* bar    = (int*)alloc(256);

  prep_kernel<<<14, 256, 0, stream>>>(mask, idxv, seg, mstart, w_masklin, ddi,
                                      mw, hX, bar);   // hX & hY contiguous

  xp_gemm<<<dim3(24576, 2), 256, 0, stream>>>(x_c, x_p, wih_c, wih_p,
                                              bih_c, bih_p, xp);

  mpnn_mol<<<NMOL_N, 256, 0, stream>>>(fingerprints, embed_fp, adj, mstart,
                                       w_g0, b_g0, w_g1, b_g1, mol);
  mpnn_emb_k<<<LBL, 256, 0, stream>>>(avg, mol, embT);

  gru_persist<<<256, 256, 0, stream>>>(xp, whh_c, whh_p, bhh_c, bhh_p,
                                       hX, hY, hcat, idxv, bar);

  gemm_f32<<<256, 256, 0, stream>>>(hcat, w_query, b_query, query, BB, HH, 2 * HH);
  tail_fused<<<BB, 256, 0, stream>>>(query, embT, w_out, b_out, gamma, beta,
                                     w_bip, b_bip, mw, out);
}

// Round 8
// 1045.715 us; speedup vs baseline: 2.4355x; 2.4355x over previous
//
#include <hip/hip_runtime.h>
#include <hip/hip_bf16.h>

#define BB 256
#define SS 32
#define II 128
#define HH 256
#define LBL 200
#define NSUBS 491
#define NATOMS_N 8000
#define NMOL_N 600

typedef const float* fp;

__device__ __forceinline__ float sigm(float x) { return 1.f / (1.f + expf(-x)); }

// ---------------------------------------------------------------------------
// prep (134 blocks): idxv, mstart, masked w_masklin, and packed GRU weights
// wP[g][k4][row(768)][4] where wP[g][k4][row][c] = whh_g[row][k4*4+c]
// (row = gate*256 + j). Lane-consecutive float4 reads in the GRU kernel.
// ---------------------------------------------------------------------------
__global__ __launch_bounds__(256) void prep_kernel(
    const int* __restrict__ mask, int* __restrict__ idxv,
    const int* __restrict__ seg, int* __restrict__ mstart,
    fp w_masklin, fp ddi, float* __restrict__ mw,
    fp whh_c, fp whh_p, float* __restrict__ wP)
{
  int bx = blockIdx.x, tid = threadIdx.x;
  if (bx == 0) {                         // idx[b] = clamp(sum(mask[b,:]) - 1)
    int s = 0;
    const int* mrow = mask + tid * SS;
    for (int t = 0; t < SS; ++t) s += mrow[t];
    s -= 1;
    if (s < 0) s = 0;
    if (s > SS - 1) s = SS - 1;
    idxv[tid] = s;
  } else if (bx == 1) {                  // mstart[m] = lower_bound(seg, m)
    for (int m = tid; m <= NMOL_N; m += 256) {
      if (m == NMOL_N) { mstart[m] = NATOMS_N; continue; }
      int lo = 0, hi = NATOMS_N;
      while (lo < hi) {
        int mid = (lo + hi) >> 1;
        if (seg[mid] < m) lo = mid + 1; else hi = mid;
      }
      mstart[m] = lo;
    }
  } else if (bx < 6) {                   // mw[s][l] = w_masklin[s][l]*ddi[l][s]
    for (int o = (bx - 2) * 256 + tid; o < NSUBS * LBL; o += 4 * 256) {
      int s = o / LBL, l = o - s * LBL;
      mw[o] = w_masklin[o] * ddi[l * NSUBS + s];
    }
  } else {                               // weight pack: one (g, k4) per block
    int lin = bx - 6;                    // 0..127
    int g = lin >> 6;
    int k4 = lin & 63;
    fp whh = g ? whh_p : whh_c;
    float* dst = wP + (size_t)g * 196608 + (size_t)k4 * 3072;
#pragma unroll
    for (int gate = 0; gate < 3; ++gate) {
      int row = gate * 256 + tid;
      float4 v = *(const float4*)(whh + (size_t)row * HH + k4 * 4);
      *(float4*)(dst + row * 4) = v;
    }
  }
}

// ---------------------------------------------------------------------------
// xp = x @ w_ih.T + b_ih, fp32. xp[g][b*SS+t][768], 8192 rows per g.
// grid (24576, 2): 512 mtiles x 48 ntiles
// ---------------------------------------------------------------------------
__global__ __launch_bounds__(256) void xp_gemm(
    fp x_c, fp x_p, fp wih_c, fp wih_p, fp bih_c, fp bih_p,
    float* __restrict__ xp)
{
  int g = blockIdx.y;
  fp x = g ? x_p : x_c;
  fp wih = g ? wih_p : wih_c;
  fp bih = g ? bih_p : bih_c;
  float* xpo = xp + (size_t)g * 8192 * 768;

  int bx = blockIdx.x;
  int mt = bx / 48, nt = bx - mt * 48;
  int m0 = mt << 4, n0 = nt << 4;
  int tid = threadIdx.x;

  __shared__ float As[16][132];
  __shared__ float Ws[16][132];
  for (int i = tid; i < 2048; i += 256) {
    int r = i >> 7, k = i & 127;
    As[r][k] = x[(size_t)(m0 + r) * II + k];
    Ws[r][k] = wih[(size_t)(n0 + r) * II + k];
  }
  __syncthreads();

  int ni = tid & 15, mi = tid >> 4;
  float acc = 0.f;
#pragma unroll 8
  for (int k = 0; k < II; ++k) acc = fmaf(As[mi][k], Ws[ni][k], acc);
  xpo[(size_t)(m0 + mi) * 768 + n0 + ni] = acc + bih[n0 + ni];
}

// ---------------------------------------------------------------------------
// fully-fused MPNN: one block per molecule (<=14 atoms).
// ---------------------------------------------------------------------------
__global__ __launch_bounds__(256) void mpnn_mol(
    const int* __restrict__ fingerprints, fp embed_fp, fp adj,
    const int* __restrict__ mstart, fp w_g0, fp b_g0, fp w_g1, fp b_g1,
    float* __restrict__ mol)
{
  int m = blockIdx.x, tid = threadIdx.x;
  int a0 = mstart[m], a1 = mstart[m + 1];
  int sz = a1 - a0;
  if (sz < 0) sz = 0;
  if (sz > 14) sz = 14;

  __shared__ float v[14][260];
  __shared__ float adjb[14][16];

#pragma unroll
  for (int i = 0; i < 14; ++i) {
    float val = 0.f;
    if (i < sz) {
      int f = fingerprints[a0 + i] & 1023;
      val = embed_fp[(size_t)f * HH + tid];
    }
    v[i][tid] = val;
  }
  if (tid < 224) {
    int i = tid >> 4, jj = tid & 15;
    float a = 0.f;
    if (i < sz && jj < sz)
      a = adj[(size_t)(a0 + i) * NATOMS_N + a0 + jj];
    adjb[i][jj] = a;
  }
  __syncthreads();

  float acc[14];
  for (int rd = 0; rd < 2; ++rd) {
    const float* wp0 = (rd ? w_g1 : w_g0) + tid;
#pragma unroll
    for (int i = 0; i < 14; ++i) acc[i] = 0.f;
    for (int k = 0; k < HH; k += 4) {
      float w0 = wp0[(size_t)k * HH];
      float w1 = wp0[(size_t)(k + 1) * HH];
      float w2 = wp0[(size_t)(k + 2) * HH];
      float w3 = wp0[(size_t)(k + 3) * HH];
#pragma unroll
      for (int i = 0; i < 14; ++i) {
        float4 vv = *(const float4*)&v[i][k];
        acc[i] = fmaf(vv.x, w0, acc[i]);
        acc[i] = fmaf(vv.y, w1, acc[i]);
        acc[i] = fmaf(vv.z, w2, acc[i]);
        acc[i] = fmaf(vv.w, w3, acc[i]);
      }
    }
    float bias = (rd ? b_g1 : b_g0)[tid];
    float hreg[14];
#pragma unroll
    for (int i = 0; i < 14; ++i) hreg[i] = fmaxf(acc[i] + bias, 0.f);
#pragma unroll
    for (int i = 0; i < 14; ++i) {
      float s = hreg[i];
#pragma unroll
      for (int jj = 0; jj < 14; ++jj) s = fmaf(adjb[i][jj], hreg[jj], s);
      acc[i] = s;
    }
    if (rd == 0) {
      __syncthreads();
#pragma unroll
      for (int i = 0; i < 14; ++i) v[i][tid] = acc[i];
      __syncthreads();
    }
  }
  float msum = 0.f;
#pragma unroll
  for (int i = 0; i < 14; ++i) if (i < sz) msum += acc[i];
  mol[(size_t)m * HH + tid] = msum;
}

// ---------------------------------------------------------------------------
// mpnn_emb^T[h][d] = sum_m avg[d][m] * mol[m][h]
// ---------------------------------------------------------------------------
__global__ __launch_bounds__(256) void mpnn_emb_k(
    fp avg, const float* __restrict__ mol, float* __restrict__ embT)
{
  int d = blockIdx.x, tid = threadIdx.x;
  float acc = 0.f;
  for (int m = 0; m < NMOL_N; ++m)
    acc += avg[d * NMOL_N + m] * mol[(size_t)m * HH + tid];
  embT[(size_t)tid * LBL + d] = acc;
}

// ---------------------------------------------------------------------------
// GRU with block-local h: 256 blocks = g(2) x 128 batch-pairs. Each block
// owns 2 complete batches; h stays in LDS across all 32 steps -> no grid
// barrier, no fences. Weights streamed from (XCD-L2-resident) packed wP;
// lane ji owns output j=ji for both batches (6 accumulators).
// ---------------------------------------------------------------------------
__global__ __launch_bounds__(256) void gru_local(
    fp xp, fp wP, fp bhh_c, fp bhh_p,
    float* __restrict__ hcat, const int* __restrict__ idxv)
{
  int blk = blockIdx.x;
  int g = blk >> 7;
  int pair = blk & 127;
  int b1 = pair * 2, b2 = pair * 2 + 1;
  int tid = threadIdx.x;               // = j
  const float* w = wP + (size_t)g * 196608;
  fp bhh = g ? bhh_p : bhh_c;
  const float* xpg = xp + (size_t)g * 8192 * 768;

  __shared__ float h1s[260];
  __shared__ float h2s[260];
  h1s[tid] = 0.f;
  h2s[tid] = 0.f;
  float br = bhh[tid], bz = bhh[tid + 256], bn = bhh[tid + 512];
  int id1 = idxv[b1], id2 = idxv[b2];
  __syncthreads();

  for (int t = 0; t < SS; ++t) {
    float s1r = 0.f, s1z = 0.f, s1n = 0.f;
    float s2r = 0.f, s2z = 0.f, s2n = 0.f;
#pragma unroll 4
    for (int k4 = 0; k4 < 64; ++k4) {
      float4 a1 = *(const float4*)&h1s[k4 * 4];
      float4 a2 = *(const float4*)&h2s[k4 * 4];
      const float* base = w + (size_t)k4 * 3072;
      float4 w0 = *(const float4*)(base + tid * 4);          // gate r
      float4 w1 = *(const float4*)(base + (256 + tid) * 4);  // gate z
      float4 w2 = *(const float4*)(base + (512 + tid) * 4);  // gate n
      s1r = fmaf(a1.x, w0.x, s1r); s1r = fmaf(a1.y, w0.y, s1r);
      s1r = fmaf(a1.z, w0.z, s1r); s1r = fmaf(a1.w, w0.w, s1r);
      s1z = fmaf(a1.x, w1.x, s1z); s1z = fmaf(a1.y, w1.y, s1z);
      s1z = fmaf(a1.z, w1.z, s1z); s1z = fmaf(a1.w, w1.w, s1z);
      s1n = fmaf(a1.x, w2.x, s1n); s1n = fmaf(a1.y, w2.y, s1n);
      s1n = fmaf(a1.z, w2.z, s1n); s1n = fmaf(a1.w, w2.w, s1n);
      s2r = fmaf(a2.x, w0.x, s2r); s2r = fmaf(a2.y, w0.y, s2r);
      s2r = fmaf(a2.z, w0.z, s2r); s2r = fmaf(a2.w, w0.w, s2r);
      s2z = fmaf(a2.x, w1.x, s2z); s2z = fmaf(a2.y, w1.y, s2z);
      s2z = fmaf(a2.z, w1.z, s2z); s2z = fmaf(a2.w, w1.w, s2z);
      s2n = fmaf(a2.x, w2.x, s2n); s2n = fmaf(a2.y, w2.y, s2n);
      s2n = fmaf(a2.z, w2.z, s2n); s2n = fmaf(a2.w, w2.w, s2n);
    }
    const float* x1 = xpg + ((size_t)b1 * SS + t) * 768;
    const float* x2 = xpg + ((size_t)b2 * SS + t) * 768;
    float r1 = sigm(x1[tid] + s1r + br);
    float z1 = sigm(x1[tid + 256] + s1z + bz);
    float n1 = tanhf(x1[tid + 512] + r1 * (s1n + bn));
    float h1new = (1.f - z1) * n1 + z1 * h1s[tid];
    float r2 = sigm(x2[tid] + s2r + br);
    float z2 = sigm(x2[tid + 256] + s2z + bz);
    float n2 = tanhf(x2[tid + 512] + r2 * (s2n + bn));
    float h2new = (1.f - z2) * n2 + z2 * h2s[tid];
    __syncthreads();                   // all h reads of this step done
    h1s[tid] = h1new;
    h2s[tid] = h2new;
    if (t == id1) hcat[(size_t)b1 * 512 + g * 256 + tid] = fmaxf(h1new, 0.f);
    if (t == id2) hcat[(size_t)b2 * 512 + g * 256 + tid] = fmaxf(h2new, 0.f);
    __syncthreads();
  }
}

// ---------------------------------------------------------------------------
// fp32 GEMM for query: C[M,N] = A[M,K] @ W[K,N] + bias
// ---------------------------------------------------------------------------
__global__ __launch_bounds__(256) void gemm_f32(
    const float* __restrict__ A, fp W, fp bias, float* __restrict__ C,
    int M, int N, int K)
{
  int ntiles = N >> 4;
  int mt = blockIdx.x / ntiles, nt = blockIdx.x - mt * ntiles;
  int m0 = mt << 4, n0 = nt << 4;
  int tid = threadIdx.x;
  int ni = tid & 15, mi = tid >> 4;
  __shared__ float As[16][68];
  float acc = 0.f;
  for (int k0 = 0; k0 < K; k0 += 64) {
    __syncthreads();
    for (int i = tid; i < 1024; i += 256) {
      int r = i >> 6, kk = i & 63;
      As[r][kk] = A[(size_t)(m0 + r) * K + k0 + kk];
    }
    __syncthreads();
    const float* wp = W + (size_t)k0 * N + n0 + ni;
#pragma unroll 4
    for (int kk = 0; kk < 64; ++kk)
      acc = fmaf(As[mi][kk], wp[(size_t)kk * N], acc);
  }
  acc += bias[n0 + ni];
  C[(size_t)(m0 + mi) * N + n0 + ni] = acc;
}

// ---------------------------------------------------------------------------
// fused tail per batch row: match/x2/LN (mpnn_att) + bip/masked-linear + mul
// ---------------------------------------------------------------------------
__global__ __launch_bounds__(256) void tail_fused(
    const float* __restrict__ query, const float* __restrict__ embT,
    fp w_out, fp b_out, fp gamma, fp beta,
    fp w_bip, fp b_bip, const float* __restrict__ mw,
    float* __restrict__ out)
{
  int b = blockIdx.x, tid = threadIdx.x;
  __shared__ float q[HH];
  __shared__ float mrow[LBL];
  __shared__ float bips[NSUBS];
  __shared__ float red[256];
  q[tid] = query[(size_t)b * HH + tid];
  __syncthreads();
  if (tid < LBL) {
    float acc = 0.f;
    for (int k = 0; k < HH; ++k) acc += q[k] * embT[(size_t)k * LBL + tid];
    mrow[tid] = sigm(acc);
  }
  for (int s = tid; s < NSUBS; s += 256) {
    float acc = b_bip[s];
    for (int k = 0; k < HH; ++k) acc += q[k] * w_bip[(size_t)k * NSUBS + s];
    bips[s] = acc;
  }
  __syncthreads();
  float x2 = 0.f;
  if (tid < LBL) {
    float acc = b_out[tid] + mrow[tid];
    for (int jj = 0; jj < LBL; ++jj) acc += mrow[jj] * w_out[jj * LBL + tid];
    x2 = acc;
  }
  red[tid] = (tid < LBL) ? x2 : 0.f;
  __syncthreads();
  for (int s = 128; s > 0; s >>= 1) {
    if (tid < s) red[tid] += red[tid + s];
    __syncthreads();
  }
  float mu = red[0] / (float)LBL;
  __syncthreads();
  float dv = (tid < LBL) ? (x2 - mu) : 0.f;
  red[tid] = dv * dv;
  __syncthreads();
  for (int s = 128; s > 0; s >>= 1) {
    if (tid < s) red[tid] += red[tid + s];
    __syncthreads();
  }
  float var = red[0] / (float)LBL;
  if (tid < LBL) {
    float matt = (x2 - mu) * rsqrtf(var + 1e-5f) * gamma[tid] + beta[tid];
    float acc = 0.f;
    for (int s = 0; s < NSUBS; ++s) acc += bips[s] * mw[(size_t)s * LBL + tid];
    out[(size_t)b * LBL + tid] = acc * matt;
  }
}

// ---------------------------------------------------------------------------
extern "C" void kernel_launch(void* const* d_in, const int* in_sizes, int n_in,
                              void* d_out, int out_size, void* d_ws, size_t ws_size,
                              hipStream_t stream)
{
  fp x_c   = (fp)d_in[0];
  fp x_p   = (fp)d_in[1];
  const int* mask = (const int*)d_in[2];
  fp wih_c = (fp)d_in[3];
  fp whh_c = (fp)d_in[4];
  fp bih_c = (fp)d_in[5];
  fp bhh_c = (fp)d_in[6];
  fp wih_p = (fp)d_in[7];
  fp whh_p = (fp)d_in[8];
  fp bih_p = (fp)d_in[9];
  fp bhh_p = (fp)d_in[10];
  fp w_query = (fp)d_in[11];
  fp b_query = (fp)d_in[12];
  fp w_bip = (fp)d_in[13];
  fp b_bip = (fp)d_in[14];
  fp w_masklin = (fp)d_in[15];
  fp ddi = (fp)d_in[16];
  fp embed_fp = (fp)d_in[17];
  const int* fingerprints = (const int*)d_in[18];
  fp adj = (fp)d_in[19];
  const int* seg = (const int*)d_in[20];
  fp w_g0 = (fp)d_in[21];
  fp b_g0 = (fp)d_in[22];
  fp w_g1 = (fp)d_in[23];
  fp b_g1 = (fp)d_in[24];
  fp avg = (fp)d_in[25];
  fp w_out = (fp)d_in[26];
  fp b_out = (fp)d_in[27];
  fp gamma = (fp)d_in[28];
  fp beta = (fp)d_in[29];
  float* out = (float*)d_out;

  char* w = (char*)d_ws;
  size_t off = 0;
  auto alloc = [&](size_t bytes) -> void* {
    void* p = w + off;
    off = (off + bytes + 255) & ~(size_t)255;
    return p;
  };

  float* xp   = (float*)alloc((size_t)2 * 8192 * 768 * 4);   // 50.3 MB
  float* wP   = (float*)alloc((size_t)2 * 196608 * 4);       // 1.57 MB
  float* mol  = (float*)alloc((size_t)NMOL_N * HH * 4);
  float* embT = (float*)alloc((size_t)HH * LBL * 4);
  float* hcat = (float*)alloc((size_t)BB * 2 * HH * 4);
  float* query = (float*)alloc((size_t)BB * HH * 4);
  float* mw   = (float*)alloc((size_t)NSUBS * LBL * 4);
  int* idxv   = (int*)alloc(256 * 4);
  int* mstart = (int*)alloc((NMOL_N + 1) * 4);

  prep_kernel<<<134, 256, 0, stream>>>(mask, idxv, seg, mstart, w_masklin, ddi,
                                       mw, whh_c, whh_p, wP);

  xp_gemm<<<dim3(24576, 2), 256, 0, stream>>>(x_c, x_p, wih_c, wih_p,
                                              bih_c, bih_p, xp);

  mpnn_mol<<<NMOL_N, 256, 0, stream>>>(fingerprints, embed_fp, adj, mstart,
                                       w_g0, b_g0, w_g1, b_g1, mol);
  mpnn_emb_k<<<LBL, 256, 0, stream>>>(avg, mol, embT);

  gru_local<<<256, 256, 0, stream>>>(xp, wP, bhh_c, bhh_p, hcat, idxv);

  gemm_f32<<<256, 256, 0, stream>>>(hcat, w_query, b_query, query, BB, HH, 2 * HH);
  tail_fused<<<BB, 256, 0, stream>>>(query, embT, w_out, b_out, gamma, beta,
                                     w_bip, b_bip, mw, out);
}